// Round 1
// baseline (862.807 us; speedup 1.0000x reference)
//
#include <hip/hip_runtime.h>

#define TT 2048
#define BATCH 256
#define LDC 132   // padded column stride: 132/4=33 (odd) -> conflict-free ds_*_b128 column access
#define NCOL 130  // 128 matrix columns + 2 RHS columns

// ws layout (floats): [0..127]=Q[:,0], [128..255]=Q[:,1], [256..]=h (B*T*2 floats, 4 MB)

__global__ __launch_bounds__(256) void prep_kernel(
    const float* __restrict__ u, const float* __restrict__ matB,
    const float* __restrict__ wIn, const float* __restrict__ wRec,
    float* __restrict__ ws)
{
    if (blockIdx.x == 0) {
        // ---- Solve (I+A) v_c = e_c (c=0,1), then q_c = (I-A) v_c ----
        __shared__ __align__(16) float Mc[NCOL * LDC]; // column-major: Mc[j*LDC + i]
        __shared__ __align__(16) float fb[128];
        __shared__ float vb[256];
        const int tid = threadIdx.x;

        for (int e = tid; e < 128 * 128; e += 256) {
            int i = e >> 7, j = e & 127;
            float a = matB[i * 128 + j] - matB[j * 128 + i]; // A[i][j]
            Mc[j * LDC + i] = a + ((i == j) ? 1.0f : 0.0f);
        }
        for (int i = tid; i < 128; i += 256) {
            Mc[128 * LDC + i] = (i == 0) ? 1.0f : 0.0f; // RHS e0
            Mc[129 * LDC + i] = (i == 1) ? 1.0f : 0.0f; // RHS e1
        }
        __syncthreads();

        // forward elimination (no pivoting: sym part of I+A is I, SPD -> stable)
        for (int k = 0; k < 127; ++k) {
            if (tid > k && tid < 128)
                fb[tid] = Mc[k * LDC + tid] / Mc[k * LDC + k];
            __syncthreads();
            int j = tid;
            if (j > k && j < NCOL) {
                float mkj = Mc[j * LDC + k];
                int i = k + 1;
                int iv = (i + 3) & ~3;
                if (iv > 128) iv = 128;
                for (; i < iv; ++i)
                    Mc[j * LDC + i] = fmaf(-fb[i], mkj, Mc[j * LDC + i]);
                for (; i < 128; i += 4) {
                    float4 m = *(float4*)&Mc[j * LDC + i];
                    float4 f = *(const float4*)&fb[i];
                    m.x = fmaf(-f.x, mkj, m.x);
                    m.y = fmaf(-f.y, mkj, m.y);
                    m.z = fmaf(-f.z, mkj, m.z);
                    m.w = fmaf(-f.w, mkj, m.w);
                    *(float4*)&Mc[j * LDC + i] = m;
                }
            }
            __syncthreads();
        }

        // back substitution, two RHS held in registers per row-thread
        float r0 = 0.f, r1 = 0.f;
        if (tid < 128) {
            r0 = Mc[128 * LDC + tid];
            r1 = Mc[129 * LDC + tid];
        }
        for (int k = 127; k >= 0; --k) {
            if (tid == k) {
                float piv = Mc[k * LDC + k];
                vb[k]       = r0 / piv;
                vb[128 + k] = r1 / piv;
            }
            __syncthreads();
            if (tid < k) {
                float uik = Mc[k * LDC + tid];
                r0 = fmaf(-uik, vb[k],       r0);
                r1 = fmaf(-uik, vb[128 + k], r1);
            }
        }
        __syncthreads();

        // q_c = v_c - A v_c
        if (tid < 128) {
            int i = tid;
            float q0 = vb[i], q1 = vb[128 + i];
            for (int j = 0; j < 128; ++j) {
                float aij = matB[i * 128 + j] - matB[j * 128 + i];
                q0 = fmaf(-aij, vb[j],       q0);
                q1 = fmaf(-aij, vb[128 + j], q1);
            }
            ws[i]       = q0;
            ws[128 + i] = q1;
        }
    } else {
        // ---- leaky RNN: one thread per batch element, runs concurrent with GE block ----
        int b = threadIdx.x;
        const float4* up4 = reinterpret_cast<const float4*>(u + (size_t)b * TT * 3);
        float4* hp4 = reinterpret_cast<float4*>(ws + 256 + (size_t)b * TT * 2);
        float a00 = 0.1f * wRec[0], a01 = 0.1f * wRec[1];
        float a10 = 0.1f * wRec[2], a11 = 0.1f * wRec[3];
        float w00 = 0.1f * wIn[0], w01 = 0.1f * wIn[1], w02 = 0.1f * wIn[2];
        float w10 = 0.1f * wIn[3], w11 = 0.1f * wIn[4], w12 = 0.1f * wIn[5];
        float y0 = 0.f, y1 = 0.f;

#define STEP(u0, u1, u2, o0, o1) { \
        float d0 = fmaf((u0), w00, fmaf((u1), w01, (u2) * w02)); \
        float d1 = fmaf((u0), w10, fmaf((u1), w11, (u2) * w12)); \
        float rr0 = fmaxf(y0, 0.f), rr1 = fmaxf(y1, 0.f); \
        float n0 = fmaf(rr0, a00, fmaf(rr1, a01, d0)); \
        float n1 = fmaf(rr0, a10, fmaf(rr1, a11, d1)); \
        y0 = fmaf(0.9f, y0, n0); \
        y1 = fmaf(0.9f, y1, n1); \
        (o0) = y0; (o1) = y1; }

        for (int g = 0; g < TT / 4; ++g) {
            float4 ua = up4[g * 3 + 0];
            float4 ub = up4[g * 3 + 1];
            float4 uc = up4[g * 3 + 2];
            float4 ha, hb;
            STEP(ua.x, ua.y, ua.z, ha.x, ha.y)
            STEP(ua.w, ub.x, ub.y, ha.z, ha.w)
            STEP(ub.z, ub.w, uc.x, hb.x, hb.y)
            STEP(uc.y, uc.z, uc.w, hb.z, hb.w)
            hp4[g * 2 + 0] = ha;
            hp4[g * 2 + 1] = hb;
        }
#undef STEP
    }
}

// out[b,t,:] = h0 * Q[:,0] + h1 * Q[:,1]; 32 lanes per (b,t), float4 per lane
__global__ __launch_bounds__(256) void out_kernel(
    const float* __restrict__ ws, float* __restrict__ out)
{
    const int tid = threadIdx.x;
    const int jg  = tid & 31;
    const int sub = tid >> 5;
    float4 qa = *(const float4*)(ws + jg * 4);
    float4 qb = *(const float4*)(ws + 128 + jg * 4);
    const float* h = ws + 256;
    const int ngroups = BATCH * TT / 8; // 65536
    for (int g = blockIdx.x; g < ngroups; g += gridDim.x) {
        size_t bt = (size_t)g * 8 + sub;
        float2 hv = *(const float2*)(h + bt * 2);
        float4 o;
        o.x = hv.x * qa.x + hv.y * qb.x;
        o.y = hv.x * qa.y + hv.y * qb.y;
        o.z = hv.x * qa.z + hv.y * qb.z;
        o.w = hv.x * qa.w + hv.y * qb.w;
        *(float4*)(out + bt * 128 + jg * 4) = o;
    }
}

extern "C" void kernel_launch(void* const* d_in, const int* in_sizes, int n_in,
                              void* d_out, int out_size, void* d_ws, size_t ws_size,
                              hipStream_t stream) {
    const float* u    = (const float*)d_in[0];
    const float* matB = (const float*)d_in[1];
    const float* wIn  = (const float*)d_in[2];
    const float* wRec = (const float*)d_in[3];
    float* out = (float*)d_out;
    float* ws  = (float*)d_ws;

    // block 0: Cayley solve (2 columns of Q); block 1: 256 RNN chains
    hipLaunchKernelGGL(prep_kernel, dim3(2), dim3(256), 0, stream, u, matB, wIn, wRec, ws);
    hipLaunchKernelGGL(out_kernel, dim3(4096), dim3(256), 0, stream, ws, out);
}

// Round 3
// 504.563 us; speedup vs baseline: 1.7100x; 1.7100x over previous
//
#include <hip/hip_runtime.h>

#define TT 2048
#define BATCH 256
#define LDC 132   // padded column stride: 132/4=33 (odd) -> conflict-free-ish column b128 access
#define NCOL 130  // 128 matrix columns + 2 RHS columns

typedef float vfloat4 __attribute__((ext_vector_type(4)));

// ws float layout:
//   [0..127]   = Q[:,0]
//   [128..255] = Q[:,1]
//   [256..256+TT*BATCH*2) = d / h buffer, layout [T][B][2] (in-place: RNN overwrites d with h)

// ---------------------------------------------------------------------------
// Kernel 1: input projection + transpose.  d[t][b][c] = 0.1 * (wIn[c] . u[b,t,:])
// Coalesced u reads (768 B contiguous per wave), LDS tile transpose, coalesced d writes.
__global__ __launch_bounds__(256) void proj_kernel(
    const float* __restrict__ u, const float* __restrict__ wIn, float* __restrict__ ws)
{
    __shared__ float2 tile[64][33]; // [t_local][b_local], padded
    const int tid = threadIdx.x;
    const int tb = blockIdx.x & 31;  // t-tile 0..31
    const int bb = blockIdx.x >> 5;  // b-tile 0..7
    const int t0 = tb * 64;
    const int b0 = bb * 32;

    const float w00 = 0.1f * wIn[0], w01 = 0.1f * wIn[1], w02 = 0.1f * wIn[2];
    const float w10 = 0.1f * wIn[3], w11 = 0.1f * wIn[4], w12 = 0.1f * wIn[5];

    const int tl  = tid & 63;   // t_local: consecutive lanes -> consecutive t (coalesced u read)
    const int bl0 = tid >> 6;   // 0..3
#pragma unroll
    for (int s = 0; s < 8; ++s) {
        int bl = bl0 + s * 4;   // b_local 0..31
        const float* p = u + ((size_t)(b0 + bl) * TT + t0 + tl) * 3;
        float x = p[0], y = p[1], z = p[2];
        float2 dv;
        dv.x = fmaf(x, w00, fmaf(y, w01, z * w02));
        dv.y = fmaf(x, w10, fmaf(y, w11, z * w12));
        tile[tl][bl] = dv;
    }
    __syncthreads();

    float* d = ws + 256;
    const int bw  = tid & 31;   // consecutive lanes -> consecutive b (coalesced d write)
    const int tw0 = tid >> 5;   // 0..7
#pragma unroll
    for (int s = 0; s < 8; ++s) {
        int tw = tw0 + s * 8;
        *(float2*)(d + ((size_t)(t0 + tw) * BATCH + b0 + bw) * 2) = tile[tw][bw];
    }
}

// ---------------------------------------------------------------------------
// Kernel 2: block 0 = Cayley solve (2 columns of Q), block 1 = 256 RNN chains.
// Independent work items run concurrently on two CUs; duration = max of the two.
__global__ __launch_bounds__(256) void ge_rnn_kernel(
    const float* __restrict__ matB, const float* __restrict__ wRec,
    float* __restrict__ ws)
{
    if (blockIdx.x == 0) {
        // ---- Solve (I+A) v_c = e_c (c=0,1), then q_c = (I-A) v_c ----
        __shared__ __align__(16) float Mc[NCOL * LDC]; // column-major: Mc[j*LDC + i]
        __shared__ __align__(16) float fb[128];
        __shared__ float vb[256];
        const int tid = threadIdx.x;

        for (int e = tid; e < 128 * 128; e += 256) {
            int i = e >> 7, j = e & 127;
            float a = matB[i * 128 + j] - matB[j * 128 + i]; // A[i][j]
            Mc[j * LDC + i] = a + ((i == j) ? 1.0f : 0.0f);
        }
        for (int i = tid; i < 128; i += 256) {
            Mc[128 * LDC + i] = (i == 0) ? 1.0f : 0.0f; // RHS e0
            Mc[129 * LDC + i] = (i == 1) ? 1.0f : 0.0f; // RHS e1
        }
        __syncthreads();

        // forward elimination (no pivoting: sym part of I+A is I -> stable)
        for (int k = 0; k < 127; ++k) {
            if (tid > k && tid < 128)
                fb[tid] = Mc[k * LDC + tid] / Mc[k * LDC + k];
            __syncthreads();
            int j = tid;
            if (j > k && j < NCOL) {
                float mkj = Mc[j * LDC + k];
                int i = k + 1;
                int iv = (i + 3) & ~3;
                if (iv > 128) iv = 128;
                for (; i < iv; ++i)
                    Mc[j * LDC + i] = fmaf(-fb[i], mkj, Mc[j * LDC + i]);
                for (; i < 128; i += 4) {
                    float4 m = *(float4*)&Mc[j * LDC + i];
                    float4 f = *(const float4*)&fb[i];
                    m.x = fmaf(-f.x, mkj, m.x);
                    m.y = fmaf(-f.y, mkj, m.y);
                    m.z = fmaf(-f.z, mkj, m.z);
                    m.w = fmaf(-f.w, mkj, m.w);
                    *(float4*)&Mc[j * LDC + i] = m;
                }
            }
            __syncthreads();
        }

        // back substitution, two RHS held in registers per row-thread
        float r0 = 0.f, r1 = 0.f;
        if (tid < 128) {
            r0 = Mc[128 * LDC + tid];
            r1 = Mc[129 * LDC + tid];
        }
        for (int k = 127; k >= 0; --k) {
            if (tid == k) {
                float piv = Mc[k * LDC + k];
                vb[k]       = r0 / piv;
                vb[128 + k] = r1 / piv;
            }
            __syncthreads();
            if (tid < k) {
                float uik = Mc[k * LDC + tid];
                r0 = fmaf(-uik, vb[k],       r0);
                r1 = fmaf(-uik, vb[128 + k], r1);
            }
        }
        __syncthreads();

        // q_c = v_c - A v_c
        if (tid < 128) {
            int i = tid;
            float q0 = vb[i], q1 = vb[128 + i];
            for (int j = 0; j < 128; ++j) {
                float aij = matB[i * 128 + j] - matB[j * 128 + i];
                q0 = fmaf(-aij, vb[j],       q0);
                q1 = fmaf(-aij, vb[128 + j], q1);
            }
            ws[i]       = q0;
            ws[128 + i] = q1;
        }
    } else if (blockIdx.x == 1) {
        // ---- leaky RNN, coalesced: lane = b, d/h in [T][B][2], in-place ----
        const int b = threadIdx.x;
        float* dh = ws + 256;
        const float a00 = 0.1f * wRec[0], a01 = 0.1f * wRec[1];
        const float a10 = 0.1f * wRec[2], a11 = 0.1f * wRec[3];
        float y0 = 0.f, y1 = 0.f;

        const int G = 16;
        float2 cur[G], nxt[G];
#pragma unroll
        for (int k = 0; k < G; ++k)
            cur[k] = *(float2*)(dh + ((size_t)k * BATCH + b) * 2);

        for (int g = 0; g < TT / G; ++g) {
            if (g + 1 < TT / G) {
                int tn = (g + 1) * G;
#pragma unroll
                for (int k = 0; k < G; ++k)
                    nxt[k] = *(float2*)(dh + ((size_t)(tn + k) * BATCH + b) * 2);
            }
#pragma unroll
            for (int k = 0; k < G; ++k) {
                float rr0 = fmaxf(y0, 0.f), rr1 = fmaxf(y1, 0.f);
                float n0 = fmaf(rr0, a00, fmaf(rr1, a01, cur[k].x));
                float n1 = fmaf(rr0, a10, fmaf(rr1, a11, cur[k].y));
                y0 = fmaf(0.9f, y0, n0);
                y1 = fmaf(0.9f, y1, n1);
                cur[k].x = y0;
                cur[k].y = y1;
            }
#pragma unroll
            for (int k = 0; k < G; ++k)
                *(float2*)(dh + ((size_t)(g * G + k) * BATCH + b) * 2) = cur[k];
#pragma unroll
            for (int k = 0; k < G; ++k) cur[k] = nxt[k];
        }
    }
}

// ---------------------------------------------------------------------------
// Kernel 3: out[b,t,:] = h0 * Q[:,0] + h1 * Q[:,1]
// b-major iteration: each block writes 4 KB contiguous per iteration; nontemporal stores.
__global__ __launch_bounds__(256) void out_kernel(
    const float* __restrict__ ws, float* __restrict__ out)
{
    const int tid = threadIdx.x;
    const int jg  = tid & 31;   // 32 lanes cover the 128 output features (float4 each)
    const int sub = tid >> 5;   // 8 (b,t) pairs per block-iteration
    float4 qa = *(const float4*)(ws + jg * 4);
    float4 qb = *(const float4*)(ws + 128 + jg * 4);
    const float* h = ws + 256;  // [T][B][2]
    const int ngroups = BATCH * (TT / 8); // 65536: g = b*256 + tchunk
    for (int g = blockIdx.x; g < ngroups; g += gridDim.x) {
        int b = g >> 8;
        int t = (g & 255) * 8 + sub;
        float2 hv = *(const float2*)(h + ((size_t)t * BATCH + b) * 2);
        vfloat4 o;
        o.x = fmaf(hv.x, qa.x, hv.y * qb.x);
        o.y = fmaf(hv.x, qa.y, hv.y * qb.y);
        o.z = fmaf(hv.x, qa.z, hv.y * qb.z);
        o.w = fmaf(hv.x, qa.w, hv.y * qb.w);
        __builtin_nontemporal_store(o, (vfloat4*)(out + ((size_t)b * TT + t) * 128 + jg * 4));
    }
}

extern "C" void kernel_launch(void* const* d_in, const int* in_sizes, int n_in,
                              void* d_out, int out_size, void* d_ws, size_t ws_size,
                              hipStream_t stream) {
    const float* u    = (const float*)d_in[0];
    const float* matB = (const float*)d_in[1];
    const float* wIn  = (const float*)d_in[2];
    const float* wRec = (const float*)d_in[3];
    float* out = (float*)d_out;
    float* ws  = (float*)d_ws;

    hipLaunchKernelGGL(proj_kernel,   dim3(256),  dim3(256), 0, stream, u, wIn, ws);
    hipLaunchKernelGGL(ge_rnn_kernel, dim3(2),    dim3(256), 0, stream, matB, wRec, ws);
    hipLaunchKernelGGL(out_kernel,    dim3(8192), dim3(256), 0, stream, ws, out);
}